// Round 12
// baseline (1538.537 us; speedup 1.0000x reference)
//
#include <hip/hip_runtime.h>
#include <hip/hip_bf16.h>

#define NPTS 692736      // 24*41*16*44
#define NPATCH 16896     // 24*16*44

// ---------- module-scope device globals ----------
__device__ float  v12_xbuf[NPATCH*256];
__device__ float  v12_ctx[NPATCH*64];
__device__ float  v12_depth[NPATCH*41];
__device__ int    v12_ranks[NPTS];
__device__ unsigned v12_sorted[NPTS];   // packed (p<<6)|d, sorted by rank
__device__ int    v12_cnt[16384];
__device__ int    v12_start[16385];
__device__ int    v12_cursor[16384];
__device__ float  v12_bev[16384*64];
__device__ float  v12_w2[64*64*9];
__device__ float  v12_wT[768*256];
__device__ double v12_geom[24*24];

__device__ __forceinline__ void inv3_v12(const double* m, double* o){
  double a=m[0],b=m[1],c=m[2],d=m[3],e=m[4],f=m[5],g=m[6],h=m[7],i=m[8];
  double A = e*i - f*h, B = -(d*i - f*g), C = d*h - e*g;
  double det = a*A + b*B + c*C;
  double id = 1.0/det;
  o[0]=A*id;            o[1]=-(b*i - c*h)*id; o[2]=(b*f - c*e)*id;
  o[3]=B*id;            o[4]=(a*i - c*g)*id;  o[5]=-(a*f - c*d)*id;
  o[6]=C*id;            o[7]=-(a*h - b*g)*id; o[8]=(a*e - b*d)*id;
}

__global__ void zcnt_v12(){
  int gid = blockIdx.x*256 + threadIdx.x;
  if (gid < 16384) v12_cnt[gid] = 0;
}

__global__ void geom_v12(const float* rots, const float* trans, const float* intrins,
                         const float* post_rots, const float* post_trans){
  int t = threadIdx.x;
  if (t >= 24) return;
  double pr[9], it[9], r[9];
  for (int i=0;i<9;i++){
    pr[i] = (double)post_rots[t*9+i];
    it[i] = (double)intrins[t*9+i];
    r[i]  = (double)rots[t*9+i];
  }
  double ipr[9], iit[9];
  inv3_v12(pr, ipr); inv3_v12(it, iit);
  double* g = v12_geom + t*24;
  for (int i=0;i<3;i++) for(int j=0;j<3;j++){
    double s=0; for(int k=0;k<3;k++) s += r[i*3+k]*iit[k*3+j];
    g[9+i*3+j]=s;
  }
  for (int i=0;i<9;i++) g[i]   = ipr[i];
  for (int i=0;i<3;i++) g[18+i]= (double)post_trans[t*3+i];
  for (int i=0;i<3;i++) g[21+i]= (double)trans[t*3+i];
}

// transpose conv_w [256 o][768 k] -> wT [768 k][256 o]
__global__ void wt_v12(const float* cw){
  int gid = blockIdx.x*256 + threadIdx.x;
  int k = gid >> 8, o = gid & 255;
  v12_wT[gid] = cw[o*768 + k];
}

// conv1 register-blocked GEMM: block = 32 patches x 256 ch, thread = 8pp x 4ch
__global__ __launch_bounds__(256) void conv1_v12(const float* img,
    const float* cb, const float* g1, const float* b1, const float* m1, const float* v1){
  __shared__ float sp[32*36];
  __shared__ float sw[32*256];
  int tid = threadIdx.x;
  int cg = tid & 63;
  int pg = tid >> 6;
  int pbase = blockIdx.x*32;
  int im = pbase/704;

  float acc[4][8];
  #pragma unroll
  for (int j=0;j<4;j++)
    #pragma unroll
    for (int i=0;i<8;i++) acc[j][i]=0.f;

  for (int kt=0; kt<768; kt+=32){
    __syncthreads();
    for (int l = tid; l < 8192; l += 256)
      sw[l] = v12_wT[(kt + (l>>8))*256 + (l&255)];
    for (int l = tid; l < 1024; l += 256){
      int kk = l>>5, pp = l&31;
      int k = kt + kk;
      int p = pbase + pp;
      int pix = p % 704;
      int ph = pix/44, pw = pix%44;
      int c = k>>8, rem = k&255, ky = rem>>4, kx = rem&15;
      sp[kk*36+pp] = img[(size_t)im*540672 + (size_t)c*180224 +
                         (size_t)(ph*16+ky)*704 + (pw*16+kx)];
    }
    __syncthreads();
    #pragma unroll 8
    for (int kk=0; kk<32; kk++){
      float4 p0 = *(const float4*)&sp[kk*36 + pg*8];
      float4 p1 = *(const float4*)&sp[kk*36 + pg*8 + 4];
      float4 wv = *(const float4*)&sw[kk*256 + cg*4];
      float pv[8] = {p0.x,p0.y,p0.z,p0.w,p1.x,p1.y,p1.z,p1.w};
      float wa[4] = {wv.x,wv.y,wv.z,wv.w};
      #pragma unroll
      for (int j=0;j<4;j++)
        #pragma unroll
        for (int i=0;i<8;i++) acc[j][i] += wa[j]*pv[i];
    }
  }
  float sc[4], sh[4], bi[4];
  #pragma unroll
  for (int j=0;j<4;j++){
    int ch = cg*4+j;
    sc[j] = g1[ch] / sqrtf(v1[ch] + 1e-5f);
    sh[j] = b1[ch] - m1[ch]*sc[j];
    bi[j] = cb[ch];
  }
  #pragma unroll
  for (int i=0;i<8;i++){
    int p = pbase + pg*8 + i;
    float4 v;
    float t0 = (acc[0][i]+bi[0])*sc[0] + sh[0]; v.x = t0>0.f?t0:0.f;
    float t1 = (acc[1][i]+bi[1])*sc[1] + sh[1]; v.y = t1>0.f?t1:0.f;
    float t2 = (acc[2][i]+bi[2])*sc[2] + sh[2]; v.z = t2>0.f?t2:0.f;
    float t3 = (acc[3][i]+bi[3])*sc[3] + sh[3]; v.w = t3>0.f?t3:0.f;
    *(float4*)&v12_xbuf[(size_t)p*256 + cg*4] = v;
  }
}

// depth head blocked GEMM + softmax + ctx split: block = 32 patches
__global__ __launch_bounds__(256) void depth_v12(const float* dw, const float* db){
  __shared__ float sx[32*260];
  __shared__ float sdw[105*36];
  __shared__ float sy[32*112];
  int tid = threadIdx.x;
  int pbase = blockIdx.x*32;
  for (int l = tid; l < 8192; l += 256){
    int pp = l>>8, c = l&255;
    sx[pp*260+c] = v12_xbuf[(size_t)(pbase+pp)*256 + c];
  }
  for (int l = tid; l < 32*105; l += 256){
    int pp = l/105, o = l%105;
    sy[pp*112+o] = db[o];
  }
  int ppg = tid >> 4;
  int og  = tid & 15;
  for (int ch = 0; ch < 8; ch++){
    __syncthreads();
    for (int l = tid; l < 105*32; l += 256){
      int o = l>>5, c = l&31;
      sdw[o*36+c] = dw[o*256 + ch*32 + c];
    }
    __syncthreads();
    float a0[7], a1[7];
    #pragma unroll
    for (int oj=0;oj<7;oj++){ a0[oj]=0.f; a1[oj]=0.f; }
    const float* x0 = &sx[(ppg*2  )*260 + ch*32];
    const float* x1 = &sx[(ppg*2+1)*260 + ch*32];
    #pragma unroll
    for (int c4=0; c4<8; c4++){
      float4 xa = *(const float4*)&x0[c4*4];
      float4 xb = *(const float4*)&x1[c4*4];
      #pragma unroll
      for (int oj=0;oj<7;oj++){
        int o = og*7+oj;
        if (o < 105){
          float4 wv = *(const float4*)&sdw[o*36 + c4*4];
          a0[oj] += xa.x*wv.x + xa.y*wv.y + xa.z*wv.z + xa.w*wv.w;
          a1[oj] += xb.x*wv.x + xb.y*wv.y + xb.z*wv.z + xb.w*wv.w;
        }
      }
    }
    #pragma unroll
    for (int oj=0;oj<7;oj++){
      int o = og*7+oj;
      if (o < 105){
        sy[(ppg*2  )*112+o] += a0[oj];
        sy[(ppg*2+1)*112+o] += a1[oj];
      }
    }
  }
  __syncthreads();
  if (tid < 32){
    float* y = &sy[tid*112];
    float m = y[0];
    for (int i=1;i<41;i++) m = fmaxf(m, y[i]);
    float s = 0.f;
    for (int i=0;i<41;i++){ float e = expf(y[i]-m); y[i] = e; s += e; }
    float inv = 1.f/s;
    for (int i=0;i<41;i++) y[i] *= inv;
  }
  __syncthreads();
  for (int l = tid; l < 32*41; l += 256){
    int pp = l/41, dd = l%41;
    v12_depth[(size_t)(pbase+pp)*41 + dd] = sy[pp*112+dd];
  }
  for (int l = tid; l < 32*64; l += 256){
    int pp = l>>6, c = l&63;
    v12_ctx[(size_t)(pbase+pp)*64 + c] = sy[pp*112 + 41 + c];
  }
}

// voxel rank + histogram
__global__ __launch_bounds__(256) void rank_v12(){
  int idx = blockIdx.x*256 + threadIdx.x;
  if (idx >= NPTS) return;
  int im = idx / 28864;
  int r  = idx % 28864;
  int d  = r / 704; int pix = r % 704;
  int h = pix / 44, w = pix % 44;
  const double* g = v12_geom + im*24;
  double fx = (double)w * (703.0/43.0);
  double fy = (double)h * 17.0;
  double fz = 4.0 + (double)d;
  double px = fx - g[18], py = fy - g[19], pz = fz - g[20];
  double q0 = g[0]*px + g[1]*py + g[2]*pz;
  double q1 = g[3]*px + g[4]*py + g[5]*pz;
  double q2 = g[6]*px + g[7]*py + g[8]*pz;
  q0 *= q2; q1 *= q2;
  double o0 = g[9]*q0  + g[10]*q1 + g[11]*q2 + g[21];
  double o1 = g[12]*q0 + g[13]*q1 + g[14]*q2 + g[22];
  double o2 = g[15]*q0 + g[16]*q1 + g[17]*q2 + g[23];
  int cx = (int)((o0 + 51.2)/0.8);
  int cy = (int)((o1 + 51.2)/0.8);
  int cz = (int)((o2 + 10.0)/20.0);
  int rank = cx + cy*128 + cz*16384;
  bool ok = (rank >= 0 && rank < 16384);
  v12_ranks[idx] = ok ? rank : -1;
  if (ok) atomicAdd(&v12_cnt[rank], 1);
}

// exclusive scan of cnt[16384] -> start[16385]; cursor = start
__global__ __launch_bounds__(256) void scan_v12(){
  __shared__ int partial[256];
  int t = threadIdx.x;
  int base = t*64;
  int s = 0;
  for (int i=0;i<64;i++) s += v12_cnt[base+i];
  partial[t] = s;
  __syncthreads();
  for (int off=1; off<256; off<<=1){
    int v = (t>=off)? partial[t-off] : 0;
    __syncthreads();
    partial[t] += v;
    __syncthreads();
  }
  int run = (t==0)? 0 : partial[t-1];
  for (int i=0;i<64;i++){
    v12_start[base+i]  = run;
    v12_cursor[base+i] = run;
    run += v12_cnt[base+i];
  }
  if (t == 255) v12_start[16384] = run;
}

// scatter point indices into rank-sorted order (packed (p<<6)|d)
__global__ __launch_bounds__(256) void sidx_v12(){
  int idx = blockIdx.x*256 + threadIdx.x;
  if (idx >= NPTS) return;
  int rank = v12_ranks[idx];
  if (rank < 0) return;
  int im = idx / 28864;
  int r  = idx % 28864;
  int d  = r / 704; int pix = r % 704;
  int p = im*704 + pix;
  int pos = atomicAdd(&v12_cursor[rank], 1);
  v12_sorted[pos] = ((unsigned)p << 6) | (unsigned)d;
}

// per-voxel reduction: one wave per voxel, lane = channel. Writes bev + out1.
__global__ __launch_bounds__(256) void bevpool_v12(float* out1){
  int v = blockIdx.x*4 + (threadIdx.x >> 6);
  int c = threadIdx.x & 63;
  int st = v12_start[v];
  int en = v12_start[v+1];
  float acc = 0.f;
  for (int i = st; i < en; i++){
    unsigned w = v12_sorted[i];
    int p = w >> 6, d = w & 63;
    acc += v12_ctx[(size_t)p*64 + c] * v12_depth[(size_t)p*41 + d];
  }
  v12_bev[(size_t)v*64 + c] = acc;
  out1[(size_t)c*16384 + v] = acc;
}

// fold enc_w concat([bev,bev]) halves
__global__ void w2_v12(const float* enc_w){
  int gid = blockIdx.x*256 + threadIdx.x;
  if (gid >= 36864) return;
  int o = gid / 576; int rem = gid % 576;
  int ic = rem / 9, t = rem % 9;
  v12_w2[gid] = enc_w[o*1152 + ic*9 + t] + enc_w[o*1152 + (ic+64)*9 + t];
}

// conv2 3x3 SAME + BN2 + ReLU + 7x64 head, fused
__global__ __launch_bounds__(256) void conv2_v12(
    const float* eb, const float* g2, const float* b2_, const float* m2, const float* v2,
    const float* hw, const float* hb, float* out0){
  __shared__ float itile[64*100];
  __shared__ float wtile[64*72];
  __shared__ float hred[4*64*7];
  int tid = threadIdx.x;
  int og  = tid >> 6;
  int pix = tid & 63;
  int py = pix >> 3, px = pix & 7;
  int by = blockIdx.y, bx = blockIdx.x;
  for (int l = tid; l < 6400; l += 256){
    int ic = l / 100, rem = l % 100;
    int iy = rem / 10, ix = rem % 10;
    int gy = by*8 + iy - 1, gx = bx*8 + ix - 1;
    itile[l] = (gy>=0 && gy<128 && gx>=0 && gx<128) ? v12_bev[(size_t)(gy*128+gx)*64 + ic] : 0.f;
  }
  float acc[16];
  #pragma unroll
  for (int j=0;j<16;j++) acc[j]=0.f;
  for (int it=0; it<64; it+=8){
    __syncthreads();
    for (int l = tid; l < 64*72; l += 256){
      int oc = l / 72, rem = l % 72;
      wtile[l] = v12_w2[oc*576 + it*9 + rem];
    }
    __syncthreads();
    for (int icl=0; icl<8; icl++){
      int ic = it + icl;
      const float* ibase = itile + ic*100 + py*10 + px;
      float iv[9];
      #pragma unroll
      for (int t=0;t<9;t++) iv[t] = ibase[(t/3)*10 + (t%3)];
      const float* wbase = wtile + (og*16)*72 + icl*9;
      #pragma unroll
      for (int j=0;j<16;j++){
        #pragma unroll
        for (int t=0;t<9;t++) acc[j] += iv[t]*wbase[j*72+t];
      }
    }
  }
  float part[7];
  #pragma unroll
  for (int o=0;o<7;o++) part[o]=0.f;
  for (int j=0;j<16;j++){
    int oc = og*16+j;
    float scale = g2[oc]/sqrtf(v2[oc]+1e-5f);
    float shift = b2_[oc] - m2[oc]*scale;
    float v = (acc[j] + eb[oc])*scale + shift;
    v = v > 0.f ? v : 0.f;
    #pragma unroll
    for (int o=0;o<7;o++) part[o] += hw[o*64+oc]*v;
  }
  __syncthreads();
  for (int o=0;o<7;o++) hred[(og*64+pix)*7+o] = part[o];
  __syncthreads();
  if (og == 0){
    int gy = by*8+py, gx = bx*8+px;
    for (int o=0;o<7;o++){
      float s = hred[pix*7+o] + hred[(64+pix)*7+o] + hred[(128+pix)*7+o]
              + hred[(192+pix)*7+o] + hb[o];
      out0[o*16384 + gy*128 + gx] = s;
    }
  }
}

extern "C" void kernel_launch(void* const* d_in, const int* in_sizes, int n_in,
                              void* d_out, int out_size, void* d_ws, size_t ws_size,
                              hipStream_t stream){
  const float* imgs       = (const float*)d_in[0];
  const float* rots       = (const float*)d_in[1];
  const float* trans      = (const float*)d_in[2];
  const float* intrins    = (const float*)d_in[3];
  const float* post_rots  = (const float*)d_in[4];
  const float* post_trans = (const float*)d_in[5];
  const float* conv_w     = (const float*)d_in[6];
  const float* conv_b     = (const float*)d_in[7];
  const float* bn1_g      = (const float*)d_in[8];
  const float* bn1_b      = (const float*)d_in[9];
  const float* bn1_m      = (const float*)d_in[10];
  const float* bn1_v      = (const float*)d_in[11];
  const float* depth_w    = (const float*)d_in[12];
  const float* depth_b    = (const float*)d_in[13];
  const float* enc_w      = (const float*)d_in[14];
  const float* enc_b      = (const float*)d_in[15];
  const float* bn2_g      = (const float*)d_in[16];
  const float* bn2_b      = (const float*)d_in[17];
  const float* bn2_m      = (const float*)d_in[18];
  const float* bn2_v      = (const float*)d_in[19];
  const float* head_w     = (const float*)d_in[20];
  const float* head_b     = (const float*)d_in[21];

  float* out0 = (float*)d_out;          // (1,7,128,128)
  float* out1 = out0 + 114688;          // (1,64,128,128)

  zcnt_v12<<<64, 256, 0, stream>>>();
  geom_v12<<<1, 32, 0, stream>>>(rots, trans, intrins, post_rots, post_trans);
  wt_v12<<<768, 256, 0, stream>>>(conv_w);
  conv1_v12<<<NPATCH/32, 256, 0, stream>>>(imgs, conv_b, bn1_g, bn1_b, bn1_m, bn1_v);
  depth_v12<<<NPATCH/32, 256, 0, stream>>>(depth_w, depth_b);
  rank_v12<<<NPTS/256, 256, 0, stream>>>();
  scan_v12<<<1, 256, 0, stream>>>();
  sidx_v12<<<NPTS/256, 256, 0, stream>>>();
  bevpool_v12<<<4096, 256, 0, stream>>>(out1);
  w2_v12<<<144, 256, 0, stream>>>(enc_w);
  conv2_v12<<<dim3(16,16), 256, 0, stream>>>(enc_b, bn2_g, bn2_b, bn2_m, bn2_v,
                                             head_w, head_b, out0);
}